// Round 1
// baseline (11298.007 us; speedup 1.0000x reference)
//
#include <hip/hip_runtime.h>
#include <hip/hip_bf16.h>

// Problem: 3-step Euler residual block
//   for 3 steps: t = relu(conv3x3(x,w1)+b1); x = x + (1/3)*(conv3x3(t,w2)+b2)
//   out = relu(x)
// B=16, C=128, H=W=128, fp32, 'SAME' padding, cross-correlation (XLA conv).
//
// Round 0: correct fp32 direct conv, LDS-tiled, register sliding window.
// Each block: 32 out-channels x (8 rows x 16 cols) spatial tile, 256 threads.
// Thread = (oc_local, row); computes 16 contiguous pixels of one row.

#define BATCH 16
#define CH    128
#define HH    128
#define WW    128

#define OC_TILE 32
#define TH      8
#define TW      16
#define CI_CHUNK 8

#define H_STEP (1.0f/3.0f)

// MODE 0: out = relu(acc + bias)                      (first conv of a step)
// MODE 1: out = res + H_STEP*(acc + bias)             (second conv, steps 1-2)
// MODE 2: out = relu(res + H_STEP*(acc + bias))       (second conv, final step)
template<int MODE>
__global__ __launch_bounds__(256, 2)
void conv3x3_kernel(const float* __restrict__ in,
                    const float* __restrict__ w,
                    const float* __restrict__ bias,
                    const float* __restrict__ res,
                    float* __restrict__ out)
{
    __shared__ float s_in[CI_CHUNK][TH + 2][TW + 2];   // 8 x 10 x 18
    __shared__ float s_w[CI_CHUNK][OC_TILE][9];        // 8 x 32 x 9

    const int tid  = threadIdx.x;
    const int oc_l = tid >> 3;        // 0..31
    const int row  = tid & 7;         // 0..7

    const int x0 = blockIdx.x * TW;   // gridDim.x = 8
    const int y0 = blockIdx.y * TH;   // gridDim.y = 16
    const int bz = blockIdx.z;        // gridDim.z = 64 = B * (CH/OC_TILE)
    const int b   = bz >> 2;
    const int oc0 = (bz & 3) * OC_TILE;

    float acc[TW];
#pragma unroll
    for (int p = 0; p < TW; ++p) acc[p] = 0.0f;

    for (int ci0 = 0; ci0 < CH; ci0 += CI_CHUNK) {
        __syncthreads();
        // --- load input tile (with halo, zero padding) ---
        for (int i = tid; i < CI_CHUNK * (TH + 2) * (TW + 2); i += 256) {
            int ci  = i / ((TH + 2) * (TW + 2));
            int rem = i % ((TH + 2) * (TW + 2));
            int r   = rem / (TW + 2);
            int c   = rem % (TW + 2);
            int gy = y0 - 1 + r;
            int gx = x0 - 1 + c;
            float v = 0.0f;
            if (gy >= 0 && gy < HH && gx >= 0 && gx < WW)
                v = in[(((size_t)b * CH + (ci0 + ci)) * HH + gy) * WW + gx];
            s_in[ci][r][c] = v;
        }
        // --- load weight tile ---
        for (int i = tid; i < CI_CHUNK * OC_TILE * 9; i += 256) {
            int ci  = i / (OC_TILE * 9);
            int rem = i % (OC_TILE * 9);
            int oc  = rem / 9;
            int k   = rem % 9;
            s_w[ci][oc][k] = w[((size_t)(oc0 + oc) * CH + (ci0 + ci)) * 9 + k];
        }
        __syncthreads();

        // --- compute ---
#pragma unroll
        for (int ci = 0; ci < CI_CHUNK; ++ci) {
#pragma unroll
            for (int ky = 0; ky < 3; ++ky) {
                float r18[TW + 2];
#pragma unroll
                for (int j = 0; j < TW + 2; ++j)
                    r18[j] = s_in[ci][row + ky][j];
#pragma unroll
                for (int kx = 0; kx < 3; ++kx) {
                    float wv = s_w[ci][oc_l][ky * 3 + kx];
#pragma unroll
                    for (int p = 0; p < TW; ++p)
                        acc[p] = fmaf(r18[p + kx], wv, acc[p]);
                }
            }
        }
    }

    // --- epilogue ---
    const int oc = oc0 + oc_l;
    const float bv = bias[oc];
    const size_t base = (((size_t)b * CH + oc) * HH + (y0 + row)) * WW + x0;
#pragma unroll
    for (int p = 0; p < TW; ++p) {
        float v = acc[p] + bv;
        if (MODE == 0) {
            v = fmaxf(v, 0.0f);
        } else {
            v = res[base + p] + H_STEP * v;
            if (MODE == 2) v = fmaxf(v, 0.0f);
        }
        out[base + p] = v;
    }
}

extern "C" void kernel_launch(void* const* d_in, const int* in_sizes, int n_in,
                              void* d_out, int out_size, void* d_ws, size_t ws_size,
                              hipStream_t stream) {
    const float* x  = (const float*)d_in[0];
    const float* w1 = (const float*)d_in[1];
    const float* b1 = (const float*)d_in[2];
    const float* w2 = (const float*)d_in[3];
    const float* b2 = (const float*)d_in[4];
    float* xbuf = (float*)d_out;             // running x state
    float* t    = (float*)d_ws;              // 134 MB scratch for t

    dim3 grid(WW / TW, HH / TH, BATCH * (CH / OC_TILE));
    dim3 block(256);

    // Step 1 (x source = d_in)
    conv3x3_kernel<0><<<grid, block, 0, stream>>>(x, w1, b1, nullptr, t);
    conv3x3_kernel<1><<<grid, block, 0, stream>>>(t, w2, b2, x, xbuf);
    // Step 2
    conv3x3_kernel<0><<<grid, block, 0, stream>>>(xbuf, w1, b1, nullptr, t);
    conv3x3_kernel<1><<<grid, block, 0, stream>>>(t, w2, b2, xbuf, xbuf);
    // Step 3 (final relu fused)
    conv3x3_kernel<0><<<grid, block, 0, stream>>>(xbuf, w1, b1, nullptr, t);
    conv3x3_kernel<2><<<grid, block, 0, stream>>>(t, w2, b2, xbuf, xbuf);
}

// Round 3
// 795.705 us; speedup vs baseline: 14.1987x; 14.1987x over previous
//
#include <hip/hip_runtime.h>
#include <hip/hip_bf16.h>

// 3-step Euler residual block via bf16 MFMA implicit-GEMM.
//   t = relu(conv(x,w1)+b1); x += (1/3)*(conv(t,w2)+b2); x3 times; out = relu(x)
// B=16, C=128, H=W=128. Activations live as NHWC bf16 in ws (XB = x state,
// T = t). Conv as 9 tap-GEMMs: D[oc][pix] += Wtap[oc][ci] * In[ci][pix+kx-1].
// Block = one (b,y) output row: 128 oc x 128 pix, 4 waves of 64x64.
// mfma_f32_16x16x32_bf16: A[m=lane&15][k=q*8+j], B[n=lane&15][k=q*8+j] (B^T),
// D: row(m)=q*4+reg, col(n)=lane&15.  m = oc, n = pix.
//
// R2 fix: transpose_x write phase ran 16 iters (xx up to 255 -> OOB LDS reads
// + cross-row global writes racing other blocks). Needs exactly 8.

#define BATCH 16
#define CH    128
#define HH    128
#define WW    128
#define H_STEP (1.0f/3.0f)

#define CI_PAD 136   // LDS row stride in bf16 elems: 272B = 17x16B, 16B aligned,
                     // dword stride 68 == 4 (mod 32) -> <=2-way bank aliasing (free)

typedef short bf16x8 __attribute__((ext_vector_type(8)));
typedef float f32x4  __attribute__((ext_vector_type(4)));

__device__ __forceinline__ float bf2f(unsigned short u) {
    union { unsigned int i; float f; } c; c.i = ((unsigned int)u) << 16; return c.f;
}
__device__ __forceinline__ unsigned short f2bf(float f) {
    union { float f; unsigned int i; } c; c.f = f;
    unsigned int i = c.i;
    return (unsigned short)((i + 0x7FFFu + ((i >> 16) & 1u)) >> 16);  // RNE
}

// ---------------- initial transpose: x0 NCHW fp32 -> XB NHWC bf16 --------------
__global__ __launch_bounds__(256)
void transpose_x(const float* __restrict__ x, unsigned short* __restrict__ xb)
{
    __shared__ unsigned short s[128 * 132];   // [ci][x], +4 pad
    const int tid = threadIdx.x;
    const int bz  = blockIdx.x;               // 0..2047 = (b,y)
    const int b = bz >> 7, y = bz & 127;

    // read phase: coalesced along x. 128 ci x 32 float4 = 4096 items.
    #pragma unroll
    for (int it = 0; it < 16; ++it) {
        int idx = it * 256 + tid;             // 0..4095
        int ci = idx >> 5, xq = idx & 31;
        float4 v = *(const float4*)&x[(((size_t)b * CH + ci) * HH + y) * WW + xq * 4];
        uint2 p;
        p.x = (unsigned int)f2bf(v.x) | ((unsigned int)f2bf(v.y) << 16);
        p.y = (unsigned int)f2bf(v.z) | ((unsigned int)f2bf(v.w) << 16);
        *(uint2*)&s[ci * 132 + xq * 4] = p;
    }
    __syncthreads();
    // write phase: coalesced along ci. 128 x-positions x 16 cc-groups = 2048 items.
    #pragma unroll
    for (int it = 0; it < 8; ++it) {
        int idx = it * 256 + tid;             // 0..2047
        int xx = idx >> 4, cc = idx & 15;     // xx 0..127, cc 0..15
        unsigned short t[8];
        #pragma unroll
        for (int k = 0; k < 8; ++k) t[k] = s[(cc * 8 + k) * 132 + xx];
        uint4 p;
        p.x = (unsigned int)t[0] | ((unsigned int)t[1] << 16);
        p.y = (unsigned int)t[2] | ((unsigned int)t[3] << 16);
        p.z = (unsigned int)t[4] | ((unsigned int)t[5] << 16);
        p.w = (unsigned int)t[6] | ((unsigned int)t[7] << 16);
        *(uint4*)&xb[((size_t)(b * HH + y) * WW + xx) * CH + cc * 8] = p;
    }
}

// --------------- weight convert: OIHW fp32 -> [tap][oc][ci] bf16 ---------------
__global__ __launch_bounds__(256)
void convert_w(const float* __restrict__ w, unsigned short* __restrict__ wb)
{
    int idx = blockIdx.x * 256 + threadIdx.x;   // 0..16383 = oc*128+ci
    #pragma unroll
    for (int t = 0; t < 9; ++t)
        wb[t * 16384 + idx] = f2bf(w[(size_t)idx * 9 + t]);
}

// ------------------------------ conv3x3 MFMA ----------------------------------
// MODE 0: outb = bf16(relu(acc + bias))                       (conv1 -> T)
// MODE 1: outb = bf16(res + h*(acc + bias))                   (conv2 -> XB, in place)
// MODE 2: outf = relu(res + h*(acc + bias)) fp32 NCHW         (final conv2 -> d_out)
template<int MODE>
__global__ __launch_bounds__(256, 2)
void conv_mfma(const unsigned short* __restrict__ in,   // NHWC bf16
               const unsigned short* __restrict__ wb,   // [9][128][128] bf16
               const float* __restrict__ bias,
               const unsigned short* resb,              // NHWC bf16 (may alias outb)
               unsigned short* outb,                    // NHWC bf16
               float* __restrict__ outf)                // NCHW fp32
{
    __shared__ unsigned short s_in[130 * CI_PAD];  // [x+1][ci], rows 0/129 = zero halo
    __shared__ unsigned short s_w [128 * CI_PAD];  // [oc][ci]

    const int tid = threadIdx.x;
    const int bz  = blockIdx.x;                    // (b,y)
    const int b = bz >> 7, y = bz & 127;

    const int lane = tid & 63;
    const int wid  = tid >> 6;
    const int woc0 = (wid >> 1) * 64;
    const int wpx0 = (wid & 1) * 64;
    const int n16  = lane & 15;
    const int q    = lane >> 4;

    f32x4 acc[4][4];
    #pragma unroll
    for (int i = 0; i < 4; ++i)
        #pragma unroll
        for (int j = 0; j < 4; ++j) acc[i][j] = (f32x4)0.0f;

    // zero the x = -1 / x = 128 halo rows once (visible after first barrier)
    if (tid < 34) {
        int r  = (tid < 17) ? 0 : 129;
        int cc = (tid < 17) ? tid : tid - 17;
        uint4 z = {0u, 0u, 0u, 0u};
        *(uint4*)&s_in[r * CI_PAD + cc * 8] = z;
    }

    for (int ky = 0; ky < 3; ++ky) {
        const int gy = y + ky - 1;
        if (gy < 0 || gy >= HH) continue;          // whole row is zero padding (uniform)
        const size_t inrow = ((size_t)(b * HH + gy) * WW) * CH;

        for (int kx = 0; kx < 3; ++kx) {
            __syncthreads();                       // prior tap's readers done
            if (kx == 0) {
                // stage input row (128 x positions x 128 ci), 16B chunks
                #pragma unroll
                for (int it = 0; it < 8; ++it) {
                    int idx = it * 256 + tid;      // 0..2047
                    int x = idx >> 4, cc = idx & 15;
                    uint4 v = *(const uint4*)&in[inrow + (size_t)x * CH + cc * 8];
                    *(uint4*)&s_in[(x + 1) * CI_PAD + cc * 8] = v;
                }
            }
            // stage this tap's weights
            const unsigned short* wt = wb + (ky * 3 + kx) * 16384;
            #pragma unroll
            for (int it = 0; it < 8; ++it) {
                int idx = it * 256 + tid;
                int oc = idx >> 4, cc = idx & 15;
                uint4 v = *(const uint4*)&wt[oc * 128 + cc * 8];
                *(uint4*)&s_w[oc * CI_PAD + cc * 8] = v;
            }
            __syncthreads();                       // staging visible

            #pragma unroll
            for (int c0 = 0; c0 < 128; c0 += 32) {
                bf16x8 af[4], bfr[4];
                #pragma unroll
                for (int i = 0; i < 4; ++i)
                    af[i] = *(const bf16x8*)&s_w[(woc0 + i * 16 + n16) * CI_PAD + c0 + q * 8];
                #pragma unroll
                for (int j = 0; j < 4; ++j)
                    bfr[j] = *(const bf16x8*)&s_in[(wpx0 + j * 16 + n16 + kx) * CI_PAD + c0 + q * 8];
                #pragma unroll
                for (int i = 0; i < 4; ++i)
                    #pragma unroll
                    for (int j = 0; j < 4; ++j)
                        acc[i][j] = __builtin_amdgcn_mfma_f32_16x16x32_bf16(
                            af[i], bfr[j], acc[i][j], 0, 0, 0);
            }
        }
    }

    // ------------------------------ epilogue ---------------------------------
    const int ybase = (b * HH + y) * WW;
    if (MODE == 0 || MODE == 1) {
        #pragma unroll
        for (int j = 0; j < 4; ++j) {
            int x = wpx0 + j * 16 + n16;
            size_t pbase = (size_t)(ybase + x) * CH;
            #pragma unroll
            for (int i = 0; i < 4; ++i) {
                int oc0 = woc0 + i * 16 + q * 4;
                float v0 = acc[i][j][0] + bias[oc0 + 0];
                float v1 = acc[i][j][1] + bias[oc0 + 1];
                float v2 = acc[i][j][2] + bias[oc0 + 2];
                float v3 = acc[i][j][3] + bias[oc0 + 3];
                if (MODE == 0) {
                    v0 = fmaxf(v0, 0.f); v1 = fmaxf(v1, 0.f);
                    v2 = fmaxf(v2, 0.f); v3 = fmaxf(v3, 0.f);
                } else {
                    uint2 rr = *(const uint2*)&resb[pbase + oc0];
                    v0 = bf2f((unsigned short)(rr.x & 0xffff)) + H_STEP * v0;
                    v1 = bf2f((unsigned short)(rr.x >> 16))    + H_STEP * v1;
                    v2 = bf2f((unsigned short)(rr.y & 0xffff)) + H_STEP * v2;
                    v3 = bf2f((unsigned short)(rr.y >> 16))    + H_STEP * v3;
                }
                uint2 po;
                po.x = (unsigned int)f2bf(v0) | ((unsigned int)f2bf(v1) << 16);
                po.y = (unsigned int)f2bf(v2) | ((unsigned int)f2bf(v3) << 16);
                *(uint2*)&outb[pbase + oc0] = po;
            }
        }
    } else {
        // fp32 NCHW out + final relu; residual still bf16 NHWC
        #pragma unroll
        for (int i = 0; i < 4; ++i) {
            #pragma unroll
            for (int r = 0; r < 4; ++r) {
                int oc = woc0 + i * 16 + q * 4 + r;
                float bv = bias[oc];
                size_t orow = ((size_t)(b * CH + oc) * HH + y) * WW;
                #pragma unroll
                for (int j = 0; j < 4; ++j) {
                    int x = wpx0 + j * 16 + n16;
                    float v = acc[i][j][r] + bv;
                    v = bf2f(resb[(size_t)(ybase + x) * CH + oc]) + H_STEP * v;
                    outf[orow + x] = fmaxf(v, 0.f);
                }
            }
        }
    }
}

// ------------------------------------------------------------------------------
extern "C" void kernel_launch(void* const* d_in, const int* in_sizes, int n_in,
                              void* d_out, int out_size, void* d_ws, size_t ws_size,
                              hipStream_t stream) {
    const float* x0 = (const float*)d_in[0];
    const float* w1 = (const float*)d_in[1];
    const float* b1 = (const float*)d_in[2];
    const float* w2 = (const float*)d_in[3];
    const float* b2 = (const float*)d_in[4];

    const size_t NELEM = (size_t)BATCH * CH * HH * WW;       // 33,554,432
    unsigned short* XB = (unsigned short*)d_ws;              // x state, NHWC bf16
    unsigned short* T  = XB + NELEM;                         // t,       NHWC bf16

    // bf16 weights [9][128][128] x 2 sets (294,912 B each): prefer ws tail,
    // fall back to the (dead after transpose) x0 input buffer.
    unsigned short* WB1;
    if (ws_size >= NELEM * 4 + 2 * 294912)
        WB1 = T + NELEM;
    else
        WB1 = (unsigned short*)d_in[0];
    unsigned short* WB2 = WB1 + 9 * 16384;

    dim3 block(256);
    dim3 gridRow(BATCH * HH);    // 2048: one block per (b, y)

    transpose_x<<<gridRow, block, 0, stream>>>(x0, XB);      // reads x0 first
    convert_w<<<dim3(64), block, 0, stream>>>(w1, WB1);      // then x0 may be clobbered
    convert_w<<<dim3(64), block, 0, stream>>>(w2, WB2);

    // step 1
    conv_mfma<0><<<gridRow, block, 0, stream>>>(XB, WB1, b1, nullptr, T, nullptr);
    conv_mfma<1><<<gridRow, block, 0, stream>>>(T, WB2, b2, XB, XB, nullptr);
    // step 2
    conv_mfma<0><<<gridRow, block, 0, stream>>>(XB, WB1, b1, nullptr, T, nullptr);
    conv_mfma<1><<<gridRow, block, 0, stream>>>(T, WB2, b2, XB, XB, nullptr);
    // step 3 (final relu, fp32 NCHW out)
    conv_mfma<0><<<gridRow, block, 0, stream>>>(XB, WB1, b1, nullptr, T, nullptr);
    conv_mfma<2><<<gridRow, block, 0, stream>>>(T, WB2, b2, XB, nullptr, (float*)d_out);
}